// Round 5
// baseline (1010.686 us; speedup 1.0000x reference)
//
#include <hip/hip_runtime.h>

// KMeans assignment: argmin_k || X[b] - C[k] ||^2, B=65536, F=1024, K=1024.
// argmin_k (x2 - 2 X.C^T + c2) == argmin_k (c2[k] - 2 cross[b,k])  (x2 const/row).
//
//  k_split: centroids fp32 -> fp16 hi/lo, layout chi/clo[f8][col][8] (coalesced).
//  k_c2:    c2[k] = sum c^2 (fp32); zeroes the rescue-list counter.
//  k_main:  fused GEMM (fp16 split, 3 MFMA products ~22-bit mantissa) + online
//           per-row (min, argmin, 2nd-min). BM=32 x BN=512 x BK=64, 256 thr
//           (4 waves, each 32x128 out), mfma_f32_32x32x16_f16, acc=64 VGPR,
//           target 3 blocks/CU. A staged in LDS with row^k8 swizzle (bank-
//           balanced both sides); B frags read from L2 (2MB/pass, resident).
//           Tight-margin rows appended to a ws list.
//  k_rescue: EXACT float64 recompute for listed rows (true argmin), batched
//           8 rows per centroid sweep; tie -> lowest index.
//  Output: d_out is an int32 buffer (harness reads np.int32) -> raw indices.

#define NB 65536
#define ND 1024
#define NK 1024
#define BM 32
#define TAU 0.02f
#define BATCH 8

typedef _Float16 f16x8 __attribute__((ext_vector_type(8)));
typedef float f32x16 __attribute__((ext_vector_type(16)));

__device__ __forceinline__ void comb3(float& m1, int& a1, float& m2,
                                      float om1, int oa1, float om2) {
  if (om1 < m1 || (om1 == m1 && oa1 < a1)) {
    m2 = fminf(m1, om2);
    m1 = om1; a1 = oa1;
  } else {
    m2 = fminf(m2, om1);
  }
}

// ---------------- prep: centroid split (coalesced writes) ----------------
__global__ __launch_bounds__(256) void k_split(const float* __restrict__ cent,
                                               _Float16* __restrict__ chi,
                                               _Float16* __restrict__ clo) {
  const int f8 = blockIdx.x;  // 0..127
#pragma unroll
  for (int rep = 0; rep < 4; ++rep) {
    const int col = rep * 256 + threadIdx.x;
    const float* src = cent + (size_t)col * ND + f8 * 8;
    float4 a = *(const float4*)src;
    float4 b = *(const float4*)(src + 4);
    float xv[8] = {a.x, a.y, a.z, a.w, b.x, b.y, b.z, b.w};
    f16x8 hv, lv;
#pragma unroll
    for (int j = 0; j < 8; ++j) {
      float x = xv[j];
      _Float16 h = (_Float16)x;
      hv[j] = h;
      lv[j] = (_Float16)(x - (float)h);
    }
    *(f16x8*)(chi + ((size_t)f8 * NK + col) * 8) = hv;
    *(f16x8*)(clo + ((size_t)f8 * NK + col) * 8) = lv;
  }
}

__global__ __launch_bounds__(256) void k_c2(const float* __restrict__ cent,
                                            float* __restrict__ c2,
                                            int* __restrict__ cnt) {
  const int col = blockIdx.x;
  const int t = threadIdx.x;
  if (col == 0 && t == 0) *cnt = 0;  // ws is poisoned: zero the counter
  const float* src = cent + (size_t)col * ND;
  float ss = 0.f;
  for (int f = t; f < ND; f += 256) {
    float v = src[f];
    ss = fmaf(v, v, ss);
  }
#pragma unroll
  for (int m = 1; m < 64; m <<= 1) ss += __shfl_xor(ss, m, 64);
  __shared__ float sr[4];
  if ((t & 63) == 0) sr[t >> 6] = ss;
  __syncthreads();
  if (t == 0) c2[col] = sr[0] + sr[1] + sr[2] + sr[3];
}

// ---------------- main: fused distance GEMM + argmin ----------------
__global__ __launch_bounds__(256, 3) void k_main(const float* __restrict__ X,
                                                 const _Float16* __restrict__ chi,
                                                 const _Float16* __restrict__ clo,
                                                 const float* __restrict__ c2,
                                                 int* __restrict__ outIdx,
                                                 int* __restrict__ cnt,
                                                 int* __restrict__ list) {
  __shared__ f16x8 Ah[8 * BM];  // [k8][row ^ k8], 16B elems, bank-balanced
  __shared__ f16x8 Al[8 * BM];
  __shared__ float pm1[BM][4], pm2[BM][4];
  __shared__ int pa1[BM][4];
  __shared__ float c2s[NK];

  const int tid = threadIdx.x;
  const int lane = tid & 63;
  const int wn = tid >> 6;   // 0..3 : 128-col quarter
  const int lc = lane & 31;  // frag row (A) / frag col (B,C)
  const int hi = lane >> 5;  // k-half selector
  const size_t row0 = (size_t)blockIdx.x * BM;

#pragma unroll
  for (int j = 0; j < 4; ++j) c2s[tid + j * 256] = c2[tid + j * 256];
  if (tid < BM) {
#pragma unroll
    for (int j = 0; j < 4; ++j) {
      pm1[tid][j] = __builtin_inff();
      pm2[tid][j] = __builtin_inff();
      pa1[tid][j] = 0x7fffffff;
    }
  }

  // A staging: thread -> (row ar, k8 chunk ak8); 8 threads cover a row's 256B
  const int ar = tid >> 3;   // 0..31
  const int ak8 = tid & 7;   // 0..7
  const float* xptr = X + (row0 + ar) * (size_t)ND + ak8 * 8;
  const int aslot = ak8 * BM + (ar ^ ak8);  // XOR swizzle: conflict-free

  for (int pass = 0; pass < 2; ++pass) {
    f32x16 acc[4] = {};
    // B base for this pass (hi folded in as one f8 step)
    const size_t hb = (((size_t)hi * NK) + pass * 512 + wn * 128 + lc) * 8;
    const _Float16* bh = chi + hb;
    const _Float16* bl = clo + hb;

    float4 ga = *(const float4*)(xptr);
    float4 gb = *(const float4*)(xptr + 4);

    for (int ks = 0; ks < 16; ++ks) {  // BK=64: 8 f8-chunks per iter
      __syncthreads();  // previous tile's frag reads complete
      {
        float xv[8] = {ga.x, ga.y, ga.z, ga.w, gb.x, gb.y, gb.z, gb.w};
        f16x8 hv, lv;
#pragma unroll
        for (int j = 0; j < 8; ++j) {
          float x = xv[j];
          _Float16 h = (_Float16)x;
          hv[j] = h;
          lv[j] = (_Float16)(x - (float)h);
        }
        Ah[aslot] = hv;
        Al[aslot] = lv;
      }
      if (ks < 15) {  // prefetch next A chunk (one full phase of cover)
        ga = *(const float4*)(xptr + (ks + 1) * 64);
        gb = *(const float4*)(xptr + (ks + 1) * 64 + 4);
      }
      __syncthreads();  // A tile visible

#pragma unroll
      for (int sl = 0; sl < 4; ++sl) {  // four K=16 slots of BK=64
        const size_t bo = ((size_t)(ks * 8 + sl * 2)) * (NK * 8);
        f16x8 fbh[4], fbl[4], fah, fal;
#pragma unroll
        for (int fn = 0; fn < 4; ++fn) {
          fbh[fn] = *(const f16x8*)(bh + bo + fn * 256);
          fbl[fn] = *(const f16x8*)(bl + bo + fn * 256);
        }
        {
          const int k8 = sl * 2 + hi;
          const int s = k8 * BM + (lc ^ k8);
          fah = Ah[s];
          fal = Al[s];
        }
        // products outermost: RAW distance to same acc = 4 MFMAs
#pragma unroll
        for (int fn = 0; fn < 4; ++fn)
          acc[fn] = __builtin_amdgcn_mfma_f32_32x32x16_f16(fah, fbh[fn],
                                                           acc[fn], 0, 0, 0);
#pragma unroll
        for (int fn = 0; fn < 4; ++fn)
          acc[fn] = __builtin_amdgcn_mfma_f32_32x32x16_f16(fah, fbl[fn],
                                                           acc[fn], 0, 0, 0);
#pragma unroll
        for (int fn = 0; fn < 4; ++fn)
          acc[fn] = __builtin_amdgcn_mfma_f32_32x32x16_f16(fal, fbh[fn],
                                                           acc[fn], 0, 0, 0);
      }
    }

    // epilogue: v = c2[col] - 2*cross ; per-row (min, arg, 2nd-min)
    // 32x32 C layout: col = lane&31, row = (reg&3) + 8*(reg>>2) + 4*(lane>>5)
#pragma unroll
    for (int reg = 0; reg < 16; ++reg) {
      const int orow = (reg & 3) + 8 * (reg >> 2) + 4 * hi;
      float m1 = __builtin_inff(), m2 = __builtin_inff();
      int a1 = 0x7fffffff;
#pragma unroll
      for (int fn = 0; fn < 4; ++fn) {
        const int cg = pass * 512 + wn * 128 + fn * 32 + lc;
        const float v = c2s[cg] - 2.0f * acc[fn][reg];
        if (v < m1 || (v == m1 && cg < a1)) {
          m2 = m1; m1 = v; a1 = cg;
        } else {
          m2 = fminf(m2, v);
        }
      }
#pragma unroll
      for (int mk = 1; mk < 32; mk <<= 1) {  // stays within 32-lane half
        float om1 = __shfl_xor(m1, mk, 64);
        float om2 = __shfl_xor(m2, mk, 64);
        int oa1 = __shfl_xor(a1, mk, 64);
        comb3(m1, a1, m2, om1, oa1, om2);
      }
      if (lc == 0) {  // unique (orow, wn) owner; stable across passes
        float rm1 = pm1[orow][wn], rm2 = pm2[orow][wn];
        int ra1 = pa1[orow][wn];
        comb3(rm1, ra1, rm2, m1, a1, m2);
        pm1[orow][wn] = rm1;
        pm2[orow][wn] = rm2;
        pa1[orow][wn] = ra1;
      }
    }
  }
  __syncthreads();
  if (tid < BM) {
    float m1 = pm1[tid][0], m2 = pm2[tid][0];
    int a1 = pa1[tid][0];
#pragma unroll
    for (int j = 1; j < 4; ++j)
      comb3(m1, a1, m2, pm1[tid][j], pa1[tid][j], pm2[tid][j]);
    outIdx[row0 + tid] = a1;        // raw int32 index
    if (!(m2 - m1 > TAU)) {  // tight margin (or NaN) -> exact recompute
      int k = atomicAdd(cnt, 1);
      list[k] = (int)(row0 + tid);
    }
  }
}

// ------- rescue: EXACT f64 recompute, batched 8 rows per centroid sweep -------
__global__ __launch_bounds__(256) void k_rescue(const float* __restrict__ X,
                                                const float* __restrict__ cent,
                                                const int* __restrict__ cnt,
                                                const int* __restrict__ list,
                                                int* __restrict__ outIdx) {
  __shared__ float4 xs4[BATCH][ND / 4];
  __shared__ int rows_s[BATCH];
  __shared__ double x2p[BATCH][4];
  __shared__ double rmw[BATCH][4];
  __shared__ int raw_[BATCH][4];
  const int t = threadIdx.x;
  const int lane = t & 63, wv = t >> 6;
  const int count = *cnt;

  for (int chunk = blockIdx.x; chunk * BATCH < count; chunk += 256) {
    const int n = min(BATCH, count - chunk * BATCH);
    __syncthreads();  // previous chunk fully consumed
    if (t < n) rows_s[t] = list[chunk * BATCH + t];
    __syncthreads();
#pragma unroll
    for (int r = 0; r < BATCH; ++r)
      if (r < n) xs4[r][t] = ((const float4*)(X + (size_t)rows_s[r] * ND))[t];
    __syncthreads();
    // exact x2 per row in f64
#pragma unroll
    for (int r = 0; r < BATCH; ++r) {
      float4 v = xs4[r][t];
      double ss = (double)v.x * v.x + (double)v.y * v.y +
                  (double)v.z * v.z + (double)v.w * v.w;
#pragma unroll
      for (int mk = 1; mk < 64; mk <<= 1) ss += __shfl_xor(ss, mk, 64);
      if (lane == 0) x2p[r][wv] = ss;
    }
    __syncthreads();
    // dots + c2 in f64: each thread handles 4 centroids x BATCH rows
    double dt[4][BATCH] = {};
    double c2d[4] = {};
    const float* cp0 = cent + (size_t)t * ND;
    for (int f = 0; f < ND; f += 4) {
      float4 cv[4];
#pragma unroll
      for (int j = 0; j < 4; ++j)
        cv[j] = *(const float4*)(cp0 + (size_t)j * 256 * ND + f);
#pragma unroll
      for (int j = 0; j < 4; ++j)
        c2d[j] += (double)cv[j].x * cv[j].x + (double)cv[j].y * cv[j].y +
                  (double)cv[j].z * cv[j].z + (double)cv[j].w * cv[j].w;
#pragma unroll
      for (int r = 0; r < BATCH; ++r) {
        float4 xv = xs4[r][f >> 2];  // LDS broadcast
#pragma unroll
        for (int j = 0; j < 4; ++j) {
          dt[j][r] += (double)xv.x * cv[j].x + (double)xv.y * cv[j].y +
                      (double)xv.z * cv[j].z + (double)xv.w * cv[j].w;
        }
      }
    }
#pragma unroll
    for (int r = 0; r < BATCH; ++r) {
      const double x2 = x2p[r][0] + x2p[r][1] + x2p[r][2] + x2p[r][3];
      double bm = __builtin_inf();
      int ba = 0x7fffffff;
#pragma unroll
      for (int j = 0; j < 4; ++j) {
        const int c = t + j * 256;
        const double d2 = x2 - 2.0 * dt[j][r] + c2d[j];  // true distance
        if (d2 < bm || (d2 == bm && c < ba)) { bm = d2; ba = c; }
      }
#pragma unroll
      for (int mk = 1; mk < 64; mk <<= 1) {
        double ob = __shfl_xor(bm, mk, 64);
        int oa = __shfl_xor(ba, mk, 64);
        if (ob < bm || (ob == bm && oa < ba)) { bm = ob; ba = oa; }
      }
      if (lane == 0) { rmw[r][wv] = bm; raw_[r][wv] = ba; }
    }
    __syncthreads();
    if (t < n) {
      double fb = rmw[t][0];
      int fa = raw_[t][0];
#pragma unroll
      for (int j = 1; j < 4; ++j)
        if (rmw[t][j] < fb || (rmw[t][j] == fb && raw_[t][j] < fa)) {
          fb = rmw[t][j]; fa = raw_[t][j];
        }
      outIdx[rows_s[t]] = fa;
    }
  }
}

// ------- fallback: workspace-free naive fp32 (correctness insurance) -------
__global__ __launch_bounds__(256) void k_naive(const float* __restrict__ X,
                                               const float* __restrict__ cent,
                                               int* __restrict__ outIdx) {
  __shared__ float4 xs4[ND / 4];
  __shared__ float rbm[4];
  __shared__ int rba[4];
  const int row = blockIdx.x;
  const int t = threadIdx.x;
  const int lane = t & 63, wv = t >> 6;
  xs4[t] = ((const float4*)(X + (size_t)row * ND))[t];
  __syncthreads();
  const float* xs = (const float*)xs4;
  float bm = __builtin_inff();
  int ba = 0x7fffffff;
  for (int c = t; c < NK; c += 256) {
    const float* cp = cent + (size_t)c * ND;
    float s = 0.f;
#pragma unroll 4
    for (int f = 0; f < ND; f += 4) {
      float4 cv = *(const float4*)(cp + f);
      float d0 = xs[f] - cv.x, d1 = xs[f + 1] - cv.y;
      float d2_ = xs[f + 2] - cv.z, d3 = xs[f + 3] - cv.w;
      s = fmaf(d0, d0, s); s = fmaf(d1, d1, s);
      s = fmaf(d2_, d2_, s); s = fmaf(d3, d3, s);
    }
    if (s < bm || (s == bm && c < ba)) { bm = s; ba = c; }
  }
#pragma unroll
  for (int mk = 1; mk < 64; mk <<= 1) {
    float ob = __shfl_xor(bm, mk, 64);
    int oa = __shfl_xor(ba, mk, 64);
    if (ob < bm || (ob == bm && oa < ba)) { bm = ob; ba = oa; }
  }
  if (lane == 0) { rbm[wv] = bm; rba[wv] = ba; }
  __syncthreads();
  if (t == 0) {
    float fb = rbm[0];
    int fa = rba[0];
#pragma unroll
    for (int j = 1; j < 4; ++j)
      if (rbm[j] < fb || (rbm[j] == fb && rba[j] < fa)) { fb = rbm[j]; fa = rba[j]; }
    outIdx[row] = fa;
  }
}

extern "C" void kernel_launch(void* const* d_in, const int* in_sizes, int n_in,
                              void* d_out, int out_size, void* d_ws, size_t ws_size,
                              hipStream_t stream) {
  const float* X = (const float*)d_in[0];     // [65536,1024] f32
  const float* cent = (const float*)d_in[1];  // [1024,1024] f32
  int* outIdx = (int*)d_out;                  // int32 indices

  // ws layout: chi 2MB | clo 2MB | c2 4KB (64KB slot) | cnt (1KB slot) | list 256KB
  const size_t WS_NEEDED = (4u << 20) + (64u << 10) + (1u << 10) + (256u << 10);
  if (ws_size < WS_NEEDED) {
    k_naive<<<dim3(NB), dim3(256), 0, stream>>>(X, cent, outIdx);
    return;
  }
  char* ws = (char*)d_ws;
  _Float16* chi = (_Float16*)ws;
  _Float16* clo = (_Float16*)(ws + (2u << 20));
  float* c2 = (float*)(ws + (4u << 20));
  int* cnt = (int*)(ws + (4u << 20) + (64u << 10));
  int* list = (int*)(ws + (4u << 20) + (64u << 10) + (1u << 10));

  k_split<<<dim3(ND / 8), dim3(256), 0, stream>>>(cent, chi, clo);
  k_c2<<<dim3(NK), dim3(256), 0, stream>>>(cent, c2, cnt);
  k_main<<<dim3(NB / BM), dim3(256), 0, stream>>>(X, chi, clo, c2, outIdx, cnt, list);
  k_rescue<<<dim3(256), dim3(256), 0, stream>>>(X, cent, cnt, list, outIdx);
}

// Round 7
// 961.428 us; speedup vs baseline: 1.0512x; 1.0512x over previous
//
#include <hip/hip_runtime.h>

// KMeans assignment: argmin_k || X[b] - C[k] ||^2, B=65536, F=1024, K=1024.
// argmin_k (x2 - 2 X.C^T + c2) == argmin_k (c2[k] - 2 cross[b,k])  (x2 const/row).
//
//  k_split: centroids fp32 -> fp16 (single, RN), layout chi[f8][col][8].
//  k_c2:    c2[k] = sum c^2 (fp32); zeroes the rescue-list counter.
//  k_main:  PURE fp16 GEMM (1 product; dist-error std ~1.5e-2) + online per-row
//           (min, argmin, 2nd-min). BM=64 x BN=512 x BK=64 (2 col passes),
//           256 thr / 4 waves, wave-tile 64x128, mfma_f32_32x32x16_f16,
//           A double-buffered in LDS (1 barrier/k-step, XOR row^k8 slots);
//           B frags from L2 (2MB chi, L2-resident; traffic = NB/BM * 2MB).
//           Rows with margin <= TAU=0.15 (~10 sigma) -> rescue list.
//  k_rescue: EXACT float64 recompute for listed rows (true argmin), batched
//           8 rows per centroid sweep, c2 in f64 hoisted; tie -> lowest idx.
//  Output: int32 indices (d_out is an int32 buffer; verified R5 absmax=0).

#define NB 65536
#define ND 1024
#define NK 1024
#define BM 64
#define TAU 0.15f
#define BATCH 8
#define RGRID 512

typedef _Float16 f16x8 __attribute__((ext_vector_type(8)));
typedef float f32x16 __attribute__((ext_vector_type(16)));

__device__ __forceinline__ void comb3(float& m1, int& a1, float& m2,
                                      float om1, int oa1, float om2) {
  if (om1 < m1 || (om1 == m1 && oa1 < a1)) {
    m2 = fminf(m1, om2);
    m1 = om1; a1 = oa1;
  } else {
    m2 = fminf(m2, om1);
  }
}

// ---------------- prep: centroid fp16 cast (coalesced writes) ----------------
__global__ __launch_bounds__(256) void k_split(const float* __restrict__ cent,
                                               _Float16* __restrict__ chi) {
  const int f8 = blockIdx.x;  // 0..127
#pragma unroll
  for (int rep = 0; rep < 4; ++rep) {
    const int col = rep * 256 + threadIdx.x;
    const float* src = cent + (size_t)col * ND + f8 * 8;
    float4 a = *(const float4*)src;
    float4 b = *(const float4*)(src + 4);
    float xv[8] = {a.x, a.y, a.z, a.w, b.x, b.y, b.z, b.w};
    f16x8 hv;
#pragma unroll
    for (int j = 0; j < 8; ++j) hv[j] = (_Float16)xv[j];
    *(f16x8*)(chi + ((size_t)f8 * NK + col) * 8) = hv;  // 16B/lane, coalesced
  }
}

__global__ __launch_bounds__(256) void k_c2(const float* __restrict__ cent,
                                            float* __restrict__ c2,
                                            int* __restrict__ cnt) {
  const int col = blockIdx.x;
  const int t = threadIdx.x;
  if (col == 0 && t == 0) *cnt = 0;  // ws is poisoned: zero the counter
  const float* src = cent + (size_t)col * ND;
  float ss = 0.f;
  for (int f = t; f < ND; f += 256) {
    float v = src[f];
    ss = fmaf(v, v, ss);
  }
#pragma unroll
  for (int m = 1; m < 64; m <<= 1) ss += __shfl_xor(ss, m, 64);
  __shared__ float sr[4];
  if ((t & 63) == 0) sr[t >> 6] = ss;
  __syncthreads();
  if (t == 0) c2[col] = sr[0] + sr[1] + sr[2] + sr[3];
}

// ---------------- main: fused distance GEMM + argmin ----------------
__global__ __launch_bounds__(256, 2) void k_main(const float* __restrict__ X,
                                                 const _Float16* __restrict__ chi,
                                                 const float* __restrict__ c2,
                                                 int* __restrict__ outIdx,
                                                 int* __restrict__ cnt,
                                                 int* __restrict__ list) {
  __shared__ f16x8 Abuf[2][8 * BM];  // [dbuf][k8*BM + (row^k8)], 8KB each
  __shared__ float pm1[BM][4], pm2[BM][4];
  __shared__ int pa1[BM][4];
  __shared__ float c2s[NK];

  const int tid = threadIdx.x;
  const int lane = tid & 63;
  const int wn = tid >> 6;   // 0..3 : which 128-col quarter this wave owns
  const int lc = lane & 31;  // frag row (A) / frag col (B,C)
  const int hi = lane >> 5;  // k-half selector
  const size_t row0 = (size_t)blockIdx.x * BM;

#pragma unroll
  for (int j = 0; j < 4; ++j) c2s[tid + j * 256] = c2[tid + j * 256];
  ((float*)pm1)[tid] = __builtin_inff();
  ((float*)pm2)[tid] = __builtin_inff();
  ((int*)pa1)[tid] = 0x7fffffff;

  // A staging: 8 threads cover one row's 256B; two 32-row halves per k-step
  const int ar0 = tid >> 3;  // 0..31
  const int ak8 = tid & 7;   // 0..7
  const float* xptr = X + (row0 + ar0) * (size_t)ND + ak8 * 8;
  const int slot0 = ak8 * BM + (ar0 ^ ak8);
  const int slot1 = ak8 * BM + ((ar0 + 32) ^ ak8);

  for (int pass = 0; pass < 2; ++pass) {
    f32x16 acc[2][4] = {};
    const _Float16* bh =
        chi + (((size_t)hi * NK) + pass * 512 + wn * 128 + lc) * 8;

    {  // prologue: stage ks=0 into buf 0 (both row halves)
      float4 ga0 = *(const float4*)(xptr);
      float4 gb0 = *(const float4*)(xptr + 4);
      float4 ga1 = *(const float4*)(xptr + 32 * ND);
      float4 gb1 = *(const float4*)(xptr + 32 * ND + 4);
      float x0[8] = {ga0.x, ga0.y, ga0.z, ga0.w, gb0.x, gb0.y, gb0.z, gb0.w};
      float x1[8] = {ga1.x, ga1.y, ga1.z, ga1.w, gb1.x, gb1.y, gb1.z, gb1.w};
      f16x8 h0, h1;
#pragma unroll
      for (int j = 0; j < 8; ++j) {
        h0[j] = (_Float16)x0[j];
        h1[j] = (_Float16)x1[j];
      }
      Abuf[0][slot0] = h0;
      Abuf[0][slot1] = h1;
    }
    __syncthreads();

    for (int ks = 0; ks < 16; ++ks) {  // BK=64
      const int cur = ks & 1;
      float4 ga0, gb0, ga1, gb1;
      if (ks < 15) {  // issue next-tile global loads early (hide HBM latency)
        ga0 = *(const float4*)(xptr + (ks + 1) * 64);
        gb0 = *(const float4*)(xptr + (ks + 1) * 64 + 4);
        ga1 = *(const float4*)(xptr + 32 * ND + (ks + 1) * 64);
        gb1 = *(const float4*)(xptr + 32 * ND + (ks + 1) * 64 + 4);
      }
#pragma unroll
      for (int sl = 0; sl < 4; ++sl) {  // four K=16 slots of BK=64
        const size_t bo = ((size_t)(ks * 8 + sl * 2)) * (NK * 8);
        f16x8 fbh[4], fah[2];
#pragma unroll
        for (int fn = 0; fn < 4; ++fn)
          fbh[fn] = *(const f16x8*)(bh + bo + fn * 256);
        {
          const int k8 = sl * 2 + hi;
#pragma unroll
          for (int fm = 0; fm < 2; ++fm)
            fah[fm] = Abuf[cur][k8 * BM + ((fm * 32 + lc) ^ k8)];
        }
#pragma unroll
        for (int fm = 0; fm < 2; ++fm)
#pragma unroll
          for (int fn = 0; fn < 4; ++fn)
            acc[fm][fn] = __builtin_amdgcn_mfma_f32_32x32x16_f16(
                fah[fm], fbh[fn], acc[fm][fn], 0, 0, 0);
      }
      if (ks < 15) {  // convert + stage into the other buffer, single barrier
        float x0[8] = {ga0.x, ga0.y, ga0.z, ga0.w, gb0.x, gb0.y, gb0.z, gb0.w};
        float x1[8] = {ga1.x, ga1.y, ga1.z, ga1.w, gb1.x, gb1.y, gb1.z, gb1.w};
        f16x8 h0, h1;
#pragma unroll
        for (int j = 0; j < 8; ++j) {
          h0[j] = (_Float16)x0[j];
          h1[j] = (_Float16)x1[j];
        }
        Abuf[cur ^ 1][slot0] = h0;
        Abuf[cur ^ 1][slot1] = h1;
        __syncthreads();
      }
    }

    // epilogue: v = c2[col] - 2*cross ; per-row (min, arg, 2nd-min)
    // 32x32 C layout: col = lane&31, row = (reg&3) + 8*(reg>>2) + 4*(lane>>5)
#pragma unroll
    for (int fm = 0; fm < 2; ++fm) {
#pragma unroll
      for (int reg = 0; reg < 16; ++reg) {
        const int orow = fm * 32 + (reg & 3) + 8 * (reg >> 2) + 4 * hi;
        float m1 = __builtin_inff(), m2 = __builtin_inff();
        int a1 = 0x7fffffff;
#pragma unroll
        for (int fn = 0; fn < 4; ++fn) {
          const int cg = pass * 512 + wn * 128 + fn * 32 + lc;
          const float v = c2s[cg] - 2.0f * acc[fm][fn][reg];
          if (v < m1 || (v == m1 && cg < a1)) {
            m2 = m1; m1 = v; a1 = cg;
          } else {
            m2 = fminf(m2, v);
          }
        }
#pragma unroll
        for (int mk = 1; mk < 32; mk <<= 1) {  // stays within 32-lane half
          float om1 = __shfl_xor(m1, mk, 64);
          float om2 = __shfl_xor(m2, mk, 64);
          int oa1 = __shfl_xor(a1, mk, 64);
          comb3(m1, a1, m2, om1, oa1, om2);
        }
        if (lc == 0) {  // unique (orow, wn) owner; stable across passes
          float rm1 = pm1[orow][wn], rm2 = pm2[orow][wn];
          int ra1 = pa1[orow][wn];
          comb3(rm1, ra1, rm2, m1, a1, m2);
          pm1[orow][wn] = rm1;
          pm2[orow][wn] = rm2;
          pa1[orow][wn] = ra1;
        }
      }
    }
  }
  __syncthreads();
  if (tid < BM) {
    float m1 = pm1[tid][0], m2 = pm2[tid][0];
    int a1 = pa1[tid][0];
#pragma unroll
    for (int j = 1; j < 4; ++j)
      comb3(m1, a1, m2, pm1[tid][j], pa1[tid][j], pm2[tid][j]);
    outIdx[row0 + tid] = a1;  // raw int32 index
    if (!(m2 - m1 > TAU)) {   // tight margin (or NaN) -> exact recompute
      int k = atomicAdd(cnt, 1);
      list[k] = (int)(row0 + tid);
    }
  }
}

// ------- rescue: EXACT f64 recompute, batched 8 rows per centroid sweep -------
__global__ __launch_bounds__(256) void k_rescue(const float* __restrict__ X,
                                                const float* __restrict__ cent,
                                                const int* __restrict__ cnt,
                                                const int* __restrict__ list,
                                                int* __restrict__ outIdx) {
  const int count = *cnt;
  if (blockIdx.x * BATCH >= count) return;  // uniform early-exit

  __shared__ float4 xs4[BATCH][ND / 4];
  __shared__ int rows_s[BATCH];
  __shared__ double x2p[BATCH][4];
  __shared__ double rmw[BATCH][4];
  __shared__ int raw_[BATCH][4];
  const int t = threadIdx.x;
  const int lane = t & 63, wv = t >> 6;
  const float* cp0 = cent + (size_t)t * ND;

  // exact c2 for this thread's 4 centroids, once per block
  double c2d[4] = {};
  for (int f = 0; f < ND; f += 4) {
    float4 cv[4];
#pragma unroll
    for (int j = 0; j < 4; ++j)
      cv[j] = *(const float4*)(cp0 + (size_t)j * 256 * ND + f);
#pragma unroll
    for (int j = 0; j < 4; ++j)
      c2d[j] += (double)cv[j].x * cv[j].x + (double)cv[j].y * cv[j].y +
                (double)cv[j].z * cv[j].z + (double)cv[j].w * cv[j].w;
  }

  for (int chunk = blockIdx.x; chunk * BATCH < count; chunk += RGRID) {
    const int n = min(BATCH, count - chunk * BATCH);
    __syncthreads();  // previous chunk fully consumed
    if (t < n) rows_s[t] = list[chunk * BATCH + t];
    __syncthreads();
#pragma unroll
    for (int r = 0; r < BATCH; ++r)
      if (r < n) xs4[r][t] = ((const float4*)(X + (size_t)rows_s[r] * ND))[t];
    __syncthreads();
    // exact x2 per row in f64
#pragma unroll
    for (int r = 0; r < BATCH; ++r) {
      float4 v = xs4[r][t];
      double ss = (double)v.x * v.x + (double)v.y * v.y +
                  (double)v.z * v.z + (double)v.w * v.w;
#pragma unroll
      for (int mk = 1; mk < 64; mk <<= 1) ss += __shfl_xor(ss, mk, 64);
      if (lane == 0) x2p[r][wv] = ss;
    }
    __syncthreads();
    // dots in f64: each thread handles 4 centroids x BATCH rows
    double dt[4][BATCH] = {};
    for (int f = 0; f < ND; f += 4) {
      float4 cv[4];
#pragma unroll
      for (int j = 0; j < 4; ++j)
        cv[j] = *(const float4*)(cp0 + (size_t)j * 256 * ND + f);
#pragma unroll
      for (int r = 0; r < BATCH; ++r) {
        float4 xv = xs4[r][f >> 2];  // LDS broadcast
#pragma unroll
        for (int j = 0; j < 4; ++j) {
          dt[j][r] += (double)xv.x * cv[j].x + (double)xv.y * cv[j].y +
                      (double)xv.z * cv[j].z + (double)xv.w * cv[j].w;
        }
      }
    }
#pragma unroll
    for (int r = 0; r < BATCH; ++r) {
      const double x2 = x2p[r][0] + x2p[r][1] + x2p[r][2] + x2p[r][3];
      double bm = __builtin_inf();
      int ba = 0x7fffffff;
#pragma unroll
      for (int j = 0; j < 4; ++j) {
        const int c = t + j * 256;
        const double d2 = x2 - 2.0 * dt[j][r] + c2d[j];  // true distance
        if (d2 < bm || (d2 == bm && c < ba)) { bm = d2; ba = c; }
      }
#pragma unroll
      for (int mk = 1; mk < 64; mk <<= 1) {
        double ob = __shfl_xor(bm, mk, 64);
        int oa = __shfl_xor(ba, mk, 64);
        if (ob < bm || (ob == bm && oa < ba)) { bm = ob; ba = oa; }
      }
      if (lane == 0) { rmw[r][wv] = bm; raw_[r][wv] = ba; }
    }
    __syncthreads();
    if (t < n) {
      double fb = rmw[t][0];
      int fa = raw_[t][0];
#pragma unroll
      for (int j = 1; j < 4; ++j)
        if (rmw[t][j] < fb || (rmw[t][j] == fb && raw_[t][j] < fa)) {
          fb = rmw[t][j]; fa = raw_[t][j];
        }
      outIdx[rows_s[t]] = fa;
    }
  }
}

// ------- fallback: workspace-free naive fp32 (correctness insurance) -------
__global__ __launch_bounds__(256) void k_naive(const float* __restrict__ X,
                                               const float* __restrict__ cent,
                                               int* __restrict__ outIdx) {
  __shared__ float4 xs4[ND / 4];
  __shared__ float rbm[4];
  __shared__ int rba[4];
  const int row = blockIdx.x;
  const int t = threadIdx.x;
  const int lane = t & 63, wv = t >> 6;
  xs4[t] = ((const float4*)(X + (size_t)row * ND))[t];
  __syncthreads();
  const float* xs = (const float*)xs4;
  float bm = __builtin_inff();
  int ba = 0x7fffffff;
  for (int c = t; c < NK; c += 256) {
    const float* cp = cent + (size_t)c * ND;
    float s = 0.f;
#pragma unroll 4
    for (int f = 0; f < ND; f += 4) {
      float4 cv = *(const float4*)(cp + f);
      float d0 = xs[f] - cv.x, d1 = xs[f + 1] - cv.y;
      float d2_ = xs[f + 2] - cv.z, d3 = xs[f + 3] - cv.w;
      s = fmaf(d0, d0, s); s = fmaf(d1, d1, s);
      s = fmaf(d2_, d2_, s); s = fmaf(d3, d3, s);
    }
    if (s < bm || (s == bm && c < ba)) { bm = s; ba = c; }
  }
#pragma unroll
  for (int mk = 1; mk < 64; mk <<= 1) {
    float ob = __shfl_xor(bm, mk, 64);
    int oa = __shfl_xor(ba, mk, 64);
    if (ob < bm || (ob == bm && oa < ba)) { bm = ob; ba = oa; }
  }
  if (lane == 0) { rbm[wv] = bm; rba[wv] = ba; }
  __syncthreads();
  if (t == 0) {
    float fb = rbm[0];
    int fa = rba[0];
#pragma unroll
    for (int j = 1; j < 4; ++j)
      if (rbm[j] < fb || (rbm[j] == fb && rba[j] < fa)) { fb = rbm[j]; fa = rba[j]; }
    outIdx[row] = fa;
  }
}

extern "C" void kernel_launch(void* const* d_in, const int* in_sizes, int n_in,
                              void* d_out, int out_size, void* d_ws, size_t ws_size,
                              hipStream_t stream) {
  const float* X = (const float*)d_in[0];     // [65536,1024] f32
  const float* cent = (const float*)d_in[1];  // [1024,1024] f32
  int* outIdx = (int*)d_out;                  // int32 indices

  // ws layout: chi 2MB | c2 4KB (64KB slot) | cnt (1KB slot) | list 256KB
  const size_t WS_NEEDED = (2u << 20) + (64u << 10) + (1u << 10) + (256u << 10);
  if (ws_size < WS_NEEDED) {
    k_naive<<<dim3(NB), dim3(256), 0, stream>>>(X, cent, outIdx);
    return;
  }
  char* ws = (char*)d_ws;
  _Float16* chi = (_Float16*)ws;
  float* c2 = (float*)(ws + (2u << 20));
  int* cnt = (int*)(ws + (2u << 20) + (64u << 10));
  int* list = (int*)(ws + (2u << 20) + (64u << 10) + (1u << 10));

  k_split<<<dim3(ND / 8), dim3(256), 0, stream>>>(cent, chi);
  k_c2<<<dim3(NK), dim3(256), 0, stream>>>(cent, c2, cnt);
  k_main<<<dim3(NB / BM), dim3(256), 0, stream>>>(X, chi, c2, outIdx, cnt, list);
  k_rescue<<<dim3(RGRID), dim3(256), 0, stream>>>(X, cent, cnt, list, outIdx);
}